// Round 3
// baseline (3599.550 us; speedup 1.0000x reference)
//
#include <hip/hip_runtime.h>
#include <hip/hip_fp16.h>
#include <math.h>

// out = softmax(s @ X[:-1]^T) @ X[1:]
// R3: register-Q flash, BQ=64, split-K x2, 512 thr (4 q-bands x 2 D-chunks),
// BK=64. Cuts L2/L3 K+V traffic 2x vs R2 (8.6 -> 4.3 GB).

#define NQ 8191
#define NK 8191
#define DD 1024
#define KPAD 8192
#define BQ 64
#define BK 64
#define SRS 68      // SredT qrow stride (dwords): balanced banks, 16B-aligned
#define PBS 72      // Pb stride (halfs): 144B rows, balanced banks

typedef _Float16 half8 __attribute__((ext_vector_type(8)));
typedef float float4v __attribute__((ext_vector_type(4)));

__global__ void prep_k(const float* __restrict__ X, _Float16* __restrict__ Kh) {
    int idx = blockIdx.x * 256 + threadIdx.x;
    int row = idx >> 10;
    float v = (row < NK) ? X[idx] : 0.f;
    Kh[idx] = (_Float16)v;
}

__global__ void prep_vt(const float* __restrict__ X, _Float16* __restrict__ Vt) {
    __shared__ float tile[64][65];
    int d0 = blockIdx.x * 64;
    int k0 = blockIdx.y * 64;
    int tx = threadIdx.x;
    int ty = threadIdx.y;
    for (int i = 0; i < 16; ++i) {
        int k = k0 + ty * 16 + i;
        float v = (k < NK) ? X[(size_t)(k + 1) * DD + d0 + tx] : 0.f;
        tile[tx][ty * 16 + i] = v;
    }
    __syncthreads();
    for (int i = 0; i < 16; ++i) {
        int dl = ty * 16 + i;
        Vt[(size_t)(d0 + dl) * KPAD + k0 + tx] = (_Float16)tile[dl][tx];
    }
}

__launch_bounds__(512, 2)
__global__ void flash(const float* __restrict__ s,
                      const _Float16* __restrict__ Kh,
                      const _Float16* __restrict__ Vt,
                      float* __restrict__ dst,     // split: opart base; else: out
                      float* __restrict__ ml,      // split only
                      int iters, int split)
{
    __shared__ float    SredT[2][BK][SRS];   // [wc][key][qrow]
    __shared__ _Float16 Pb[BQ][PBS];
    __shared__ float    mS[BQ], lS[BQ], aS[BQ];

    const int t  = threadIdx.x;
    const int w  = t >> 6, l = t & 63;
    const int wr = w >> 1, wc = w & 1;       // 4 q-bands x 2 D-chunks
    const int ln = l & 15, q4 = l >> 4;

    int qt, kbase;
    float* dstp = dst;
    float* mlp  = ml;
    if (split) {
        int b = blockIdx.x;
        int x = b & 7, j = b >> 3;
        int ks = x & 1;                       // co-XCD blocks share a K stream
        qt    = ((x >> 1) << 5) + j;          // 0..127
        kbase = ks << 12;                     // 0 or 4096
        dstp  = dst + (size_t)ks * KPAD * DD;
        mlp   = ml  + (size_t)ks * KPAD * 2;
    } else {
        qt = blockIdx.x;
        kbase = 0;
    }
    const int q0 = qt * BQ;

    // ---- Q fragments in registers: 16 rows x 512 D per wave (fp16, 64 VGPR) ----
    half8 Qf[16];
    {
        int qg = q0 + wr * 16 + ln;
        const float* qp = s + (size_t)qg * DD + wc * 512 + q4 * 8;
        #pragma unroll
        for (int f = 0; f < 16; ++f) {
            half8 h;
            if (qg < NQ) {
                float4v f0 = *(const float4v*)(qp + f * 32);
                float4v f1 = *(const float4v*)(qp + f * 32 + 4);
                h[0]=(_Float16)f0[0]; h[1]=(_Float16)f0[1];
                h[2]=(_Float16)f0[2]; h[3]=(_Float16)f0[3];
                h[4]=(_Float16)f1[0]; h[5]=(_Float16)f1[1];
                h[6]=(_Float16)f1[2]; h[7]=(_Float16)f1[3];
            } else {
                #pragma unroll
                for (int j = 0; j < 8; ++j) h[j] = (_Float16)0.f;
            }
            Qf[f] = h;
        }
    }
    if (t < BQ) { mS[t] = -INFINITY; lS[t] = 0.f; }
    __syncthreads();

    // O accumulator: 16 rows x 512 cols per wave = 128 VGPR
    float4v oa[32];
    #pragma unroll
    for (int dt = 0; dt < 32; ++dt) oa[dt] = (float4v){0.f,0.f,0.f,0.f};

    for (int it = 0; it < iters; ++it) {
        const int kb = kbase + it * BK;

        // ---- phase 1: S_partial = Q_chunk . K_chunk^T  (64 MFMA) ----
        float4v sc[4];
        #pragma unroll
        for (int nt = 0; nt < 4; ++nt) sc[nt] = (float4v){0.f,0.f,0.f,0.f};
        const _Float16* kp = Kh + (size_t)(kb + ln) * DD + wc * 512 + q4 * 8;
        #pragma unroll
        for (int f = 0; f < 16; ++f) {
            #pragma unroll
            for (int nt = 0; nt < 4; ++nt) {
                half8 bf = *(const half8*)(kp + (size_t)nt * 16 * DD + f * 32);
                sc[nt] = __builtin_amdgcn_mfma_f32_16x16x32_f16(Qf[f], bf, sc[nt], 0, 0, 0);
            }
        }
        #pragma unroll
        for (int nt = 0; nt < 4; ++nt)
            *(float4v*)&SredT[wc][nt * 16 + ln][wr * 16 + q4 * 4] = sc[nt];
        __syncthreads();

        // ---- phase 2: reduce 2 D-chunks, online softmax over 64 new keys ----
        {
            const int row = t >> 3, sub = t & 7;   // 64 rows x 8 threads, 8 cols each
            float sv[8];
            float tm = -INFINITY;
            #pragma unroll
            for (int j = 0; j < 8; ++j) {
                int c = sub * 8 + j;
                float v = SredT[0][c][row] + SredT[1][c][row];
                v = (kb + c < NK) ? v : -INFINITY;
                sv[j] = v;
                tm = fmaxf(tm, v);
            }
            tm = fmaxf(tm, __shfl_xor(tm, 1));
            tm = fmaxf(tm, __shfl_xor(tm, 2));
            tm = fmaxf(tm, __shfl_xor(tm, 4));
            float mo = mS[row];
            float mn = fmaxf(mo, tm);
            float ts = 0.f;
            half8 ph;
            #pragma unroll
            for (int j = 0; j < 8; ++j) {
                float p = __expf(sv[j] - mn);
                ts += p;
                ph[j] = (_Float16)p;
            }
            *(half8*)&Pb[row][sub * 8] = ph;
            ts += __shfl_xor(ts, 1);
            ts += __shfl_xor(ts, 2);
            ts += __shfl_xor(ts, 4);
            if (sub == 0) {
                float al = __expf(mo - mn);
                aS[row] = al;
                mS[row] = mn;
                lS[row] = lS[row] * al + ts;
            }
        }
        __syncthreads();

        // ---- phase 3: O = O*alpha + P . V_chunk  (64 MFMA) ----
        float al[4];
        #pragma unroll
        for (int r = 0; r < 4; ++r) al[r] = aS[wr * 16 + q4 * 4 + r];
        #pragma unroll
        for (int dt = 0; dt < 32; ++dt)
            #pragma unroll
            for (int r = 0; r < 4; ++r) oa[dt][r] *= al[r];
        half8 ap0 = *(const half8*)&Pb[wr * 16 + ln][q4 * 8];
        half8 ap1 = *(const half8*)&Pb[wr * 16 + ln][32 + q4 * 8];
        const _Float16* vp0 = Vt + (size_t)(wc * 512 + ln) * KPAD + kb + q4 * 8;
        #pragma unroll 8
        for (int dt = 0; dt < 32; ++dt) {
            const _Float16* vp = vp0 + (size_t)dt * 16 * KPAD;
            half8 b0 = *(const half8*)vp;
            half8 b1 = *(const half8*)(vp + 32);
            oa[dt] = __builtin_amdgcn_mfma_f32_16x16x32_f16(ap0, b0, oa[dt], 0, 0, 0);
            oa[dt] = __builtin_amdgcn_mfma_f32_16x16x32_f16(ap1, b1, oa[dt], 0, 0, 0);
        }
    }

    // ---- epilogue ----
    if (split) {
        #pragma unroll 8
        for (int dt = 0; dt < 32; ++dt) {
            #pragma unroll
            for (int r = 0; r < 4; ++r) {
                int row = q0 + wr * 16 + q4 * 4 + r;
                dstp[(size_t)row * DD + wc * 512 + dt * 16 + ln] = oa[dt][r];
            }
        }
        if (t < BQ) {
            mlp[(size_t)(q0 + t) * 2]     = mS[t];
            mlp[(size_t)(q0 + t) * 2 + 1] = lS[t];
        }
    } else {
        float li[4];
        #pragma unroll
        for (int r = 0; r < 4; ++r) li[r] = 1.f / lS[wr * 16 + q4 * 4 + r];
        #pragma unroll 8
        for (int dt = 0; dt < 32; ++dt) {
            #pragma unroll
            for (int r = 0; r < 4; ++r) {
                int row = q0 + wr * 16 + q4 * 4 + r;
                if (row < NQ)
                    dstp[(size_t)row * DD + wc * 512 + dt * 16 + ln] = oa[dt][r] * li[r];
            }
        }
    }
}

__global__ void combine(const float* __restrict__ o0,
                        const float* __restrict__ o1,
                        const float* __restrict__ ml,
                        float* __restrict__ out)
{
    int idx = blockIdx.x * 256 + threadIdx.x;   // over NQ * 256 float4s
    int q   = idx >> 8;
    int c4  = (idx & 255) * 4;
    const float* ml0 = ml;
    const float* ml1 = ml + (size_t)KPAD * 2;
    float m0 = ml0[q * 2], l0 = ml0[q * 2 + 1];
    float m1 = ml1[q * 2], l1 = ml1[q * 2 + 1];
    float mm = fmaxf(m0, m1);
    float w0 = __expf(m0 - mm), w1 = __expf(m1 - mm);
    float inv = 1.f / (w0 * l0 + w1 * l1);
    float4v a = *(const float4v*)(o0 + (size_t)q * DD + c4);
    float4v b = *(const float4v*)(o1 + (size_t)q * DD + c4);
    float4v r;
    #pragma unroll
    for (int j = 0; j < 4; ++j) r[j] = (w0 * a[j] + w1 * b[j]) * inv;
    *(float4v*)(out + (size_t)q * DD + c4) = r;
}

extern "C" void kernel_launch(void* const* d_in, const int* in_sizes, int n_in,
                              void* d_out, int out_size, void* d_ws, size_t ws_size,
                              hipStream_t stream) {
    const float* X = (const float*)d_in[0];
    const float* s = (const float*)d_in[1];
    float* out = (float*)d_out;

    _Float16* Kh = (_Float16*)d_ws;                      // 16 MiB
    _Float16* Vt = Kh + (size_t)KPAD * DD;               // 16 MiB
    float* opart0 = (float*)((char*)d_ws + (size_t)2 * KPAD * DD * 2);
    float* opart1 = opart0 + (size_t)KPAD * DD;          // 32 MiB each
    float* mlbuf  = opart1 + (size_t)KPAD * DD;          // 128 KiB

    size_t need = (size_t)2 * KPAD * DD * 2              // Kh + Vt fp16
                + (size_t)2 * KPAD * DD * 4              // opart0/1 f32
                + (size_t)2 * KPAD * 2 * 4;              // m,l
    int split = (ws_size >= need) ? 1 : 0;

    prep_k<<<(KPAD * DD) / 256, 256, 0, stream>>>(X, Kh);
    prep_vt<<<dim3(DD / 64, KPAD / 64), dim3(64, 4), 0, stream>>>(X, Vt);

    if (split) {
        flash<<<256, 512, 0, stream>>>(s, Kh, Vt, opart0, mlbuf, 64, 1);
        combine<<<NQ, 256, 0, stream>>>(opart0, opart1, mlbuf, out);
    } else {
        flash<<<128, 512, 0, stream>>>(s, Kh, Vt, out, nullptr, 128, 0);
    }
}

// Round 4
// 3579.011 us; speedup vs baseline: 1.0057x; 1.0057x over previous
//
#include <hip/hip_runtime.h>
#include <hip/hip_fp16.h>
#include <math.h>

// out = softmax(s @ X[:-1]^T) @ X[1:]
// R4: R3 structure (register-Q flash, BQ=64, split-K x2, 512 thr) with
// __launch_bounds__(512,1) so the ~240 live VGPRs fit WITHOUT scratch spill.
// R3's (512,2) bound made the allocator spill the O-accumulator -> 8.5 GB
// of scratch HBM writes. Occupancy 8 waves/CU is fine (R2 proved occupancy
// is not the binding constraint; cache-service BW is).

#define NQ 8191
#define NK 8191
#define DD 1024
#define KPAD 8192
#define BQ 64
#define BK 64
#define SRS 68      // SredT qrow stride (dwords)
#define PBS 72      // Pb stride (halfs)

typedef _Float16 half8 __attribute__((ext_vector_type(8)));
typedef float float4v __attribute__((ext_vector_type(4)));

__global__ void prep_k(const float* __restrict__ X, _Float16* __restrict__ Kh) {
    int idx = blockIdx.x * 256 + threadIdx.x;
    int row = idx >> 10;
    float v = (row < NK) ? X[idx] : 0.f;
    Kh[idx] = (_Float16)v;
}

__global__ void prep_vt(const float* __restrict__ X, _Float16* __restrict__ Vt) {
    __shared__ float tile[64][65];
    int d0 = blockIdx.x * 64;
    int k0 = blockIdx.y * 64;
    int tx = threadIdx.x;
    int ty = threadIdx.y;
    for (int i = 0; i < 16; ++i) {
        int k = k0 + ty * 16 + i;
        float v = (k < NK) ? X[(size_t)(k + 1) * DD + d0 + tx] : 0.f;
        tile[tx][ty * 16 + i] = v;
    }
    __syncthreads();
    for (int i = 0; i < 16; ++i) {
        int dl = ty * 16 + i;
        Vt[(size_t)(d0 + dl) * KPAD + k0 + tx] = (_Float16)tile[dl][tx];
    }
}

__launch_bounds__(512, 1)
__global__ void flash(const float* __restrict__ s,
                      const _Float16* __restrict__ Kh,
                      const _Float16* __restrict__ Vt,
                      float* __restrict__ dst,     // split: opart base; else: out
                      float* __restrict__ ml,      // split only
                      int iters, int split)
{
    __shared__ float    SredT[2][BK][SRS];   // [wc][key][qrow]
    __shared__ _Float16 Pb[BQ][PBS];
    __shared__ float    mS[BQ], lS[BQ], aS[BQ];

    const int t  = threadIdx.x;
    const int w  = t >> 6, l = t & 63;
    const int wr = w >> 1, wc = w & 1;       // 4 q-bands x 2 D-chunks
    const int ln = l & 15, q4 = l >> 4;

    int qt, kbase;
    float* dstp = dst;
    float* mlp  = ml;
    if (split) {
        int b = blockIdx.x;
        int x = b & 7, j = b >> 3;
        int ks = x & 1;                       // co-XCD blocks share a K stream
        qt    = ((x >> 1) << 5) + j;          // 0..127
        kbase = ks << 12;                     // 0 or 4096
        dstp  = dst + (size_t)ks * KPAD * DD;
        mlp   = ml  + (size_t)ks * KPAD * 2;
    } else {
        qt = blockIdx.x;
        kbase = 0;
    }
    const int q0 = qt * BQ;

    // ---- Q fragments in registers: 16 rows x 512 D per wave (fp16, 64 VGPR) ----
    half8 Qf[16];
    {
        int qg = q0 + wr * 16 + ln;
        const float* qp = s + (size_t)qg * DD + wc * 512 + q4 * 8;
        #pragma unroll
        for (int f = 0; f < 16; ++f) {
            half8 h;
            if (qg < NQ) {
                float4v f0 = *(const float4v*)(qp + f * 32);
                float4v f1 = *(const float4v*)(qp + f * 32 + 4);
                h[0]=(_Float16)f0[0]; h[1]=(_Float16)f0[1];
                h[2]=(_Float16)f0[2]; h[3]=(_Float16)f0[3];
                h[4]=(_Float16)f1[0]; h[5]=(_Float16)f1[1];
                h[6]=(_Float16)f1[2]; h[7]=(_Float16)f1[3];
            } else {
                #pragma unroll
                for (int j = 0; j < 8; ++j) h[j] = (_Float16)0.f;
            }
            Qf[f] = h;
        }
    }
    if (t < BQ) { mS[t] = -INFINITY; lS[t] = 0.f; }
    __syncthreads();

    // O accumulator: 16 rows x 512 cols per wave = 128 regs (unified VGPR/AGPR)
    float4v oa[32];
    #pragma unroll
    for (int dt = 0; dt < 32; ++dt) oa[dt] = (float4v){0.f,0.f,0.f,0.f};

    for (int it = 0; it < iters; ++it) {
        const int kb = kbase + it * BK;

        // ---- phase 1: S_partial = Q_chunk . K_chunk^T  (64 MFMA) ----
        float4v sc[4];
        #pragma unroll
        for (int nt = 0; nt < 4; ++nt) sc[nt] = (float4v){0.f,0.f,0.f,0.f};
        const _Float16* kp = Kh + (size_t)(kb + ln) * DD + wc * 512 + q4 * 8;
        #pragma unroll
        for (int f = 0; f < 16; ++f) {
            #pragma unroll
            for (int nt = 0; nt < 4; ++nt) {
                half8 bf = *(const half8*)(kp + (size_t)nt * 16 * DD + f * 32);
                sc[nt] = __builtin_amdgcn_mfma_f32_16x16x32_f16(Qf[f], bf, sc[nt], 0, 0, 0);
            }
        }
        #pragma unroll
        for (int nt = 0; nt < 4; ++nt)
            *(float4v*)&SredT[wc][nt * 16 + ln][wr * 16 + q4 * 4] = sc[nt];
        __syncthreads();

        // ---- phase 2: reduce 2 D-chunks, online softmax over 64 new keys ----
        {
            const int row = t >> 3, sub = t & 7;   // 64 rows x 8 threads
            float sv[8];
            float tm = -INFINITY;
            #pragma unroll
            for (int j = 0; j < 8; ++j) {
                int c = sub * 8 + j;
                float v = SredT[0][c][row] + SredT[1][c][row];
                v = (kb + c < NK) ? v : -INFINITY;
                sv[j] = v;
                tm = fmaxf(tm, v);
            }
            tm = fmaxf(tm, __shfl_xor(tm, 1));
            tm = fmaxf(tm, __shfl_xor(tm, 2));
            tm = fmaxf(tm, __shfl_xor(tm, 4));
            float mo = mS[row];
            float mn = fmaxf(mo, tm);
            float ts = 0.f;
            half8 ph;
            #pragma unroll
            for (int j = 0; j < 8; ++j) {
                float p = __expf(sv[j] - mn);
                ts += p;
                ph[j] = (_Float16)p;
            }
            *(half8*)&Pb[row][sub * 8] = ph;
            ts += __shfl_xor(ts, 1);
            ts += __shfl_xor(ts, 2);
            ts += __shfl_xor(ts, 4);
            if (sub == 0) {
                float al = __expf(mo - mn);
                aS[row] = al;
                mS[row] = mn;
                lS[row] = lS[row] * al + ts;
            }
        }
        __syncthreads();

        // ---- phase 3: O = O*alpha + P . V_chunk  (64 MFMA) ----
        float al[4];
        #pragma unroll
        for (int r = 0; r < 4; ++r) al[r] = aS[wr * 16 + q4 * 4 + r];
        #pragma unroll
        for (int dt = 0; dt < 32; ++dt)
            #pragma unroll
            for (int r = 0; r < 4; ++r) oa[dt][r] *= al[r];
        half8 ap0 = *(const half8*)&Pb[wr * 16 + ln][q4 * 8];
        half8 ap1 = *(const half8*)&Pb[wr * 16 + ln][32 + q4 * 8];
        const _Float16* vp0 = Vt + (size_t)(wc * 512 + ln) * KPAD + kb + q4 * 8;
        #pragma unroll 8
        for (int dt = 0; dt < 32; ++dt) {
            const _Float16* vp = vp0 + (size_t)dt * 16 * KPAD;
            half8 b0 = *(const half8*)vp;
            half8 b1 = *(const half8*)(vp + 32);
            oa[dt] = __builtin_amdgcn_mfma_f32_16x16x32_f16(ap0, b0, oa[dt], 0, 0, 0);
            oa[dt] = __builtin_amdgcn_mfma_f32_16x16x32_f16(ap1, b1, oa[dt], 0, 0, 0);
        }
    }

    // ---- epilogue ----
    if (split) {
        #pragma unroll 8
        for (int dt = 0; dt < 32; ++dt) {
            #pragma unroll
            for (int r = 0; r < 4; ++r) {
                int row = q0 + wr * 16 + q4 * 4 + r;
                dstp[(size_t)row * DD + wc * 512 + dt * 16 + ln] = oa[dt][r];
            }
        }
        if (t < BQ) {
            mlp[(size_t)(q0 + t) * 2]     = mS[t];
            mlp[(size_t)(q0 + t) * 2 + 1] = lS[t];
        }
    } else {
        float li[4];
        #pragma unroll
        for (int r = 0; r < 4; ++r) li[r] = 1.f / lS[wr * 16 + q4 * 4 + r];
        #pragma unroll 8
        for (int dt = 0; dt < 32; ++dt) {
            #pragma unroll
            for (int r = 0; r < 4; ++r) {
                int row = q0 + wr * 16 + q4 * 4 + r;
                if (row < NQ)
                    dstp[(size_t)row * DD + wc * 512 + dt * 16 + ln] = oa[dt][r] * li[r];
            }
        }
    }
}

__global__ void combine(const float* __restrict__ o0,
                        const float* __restrict__ o1,
                        const float* __restrict__ ml,
                        float* __restrict__ out)
{
    int idx = blockIdx.x * 256 + threadIdx.x;   // over NQ * 256 float4s
    int q   = idx >> 8;
    int c4  = (idx & 255) * 4;
    const float* ml0 = ml;
    const float* ml1 = ml + (size_t)KPAD * 2;
    float m0 = ml0[q * 2], l0 = ml0[q * 2 + 1];
    float m1 = ml1[q * 2], l1 = ml1[q * 2 + 1];
    float mm = fmaxf(m0, m1);
    float w0 = __expf(m0 - mm), w1 = __expf(m1 - mm);
    float inv = 1.f / (w0 * l0 + w1 * l1);
    float4v a = *(const float4v*)(o0 + (size_t)q * DD + c4);
    float4v b = *(const float4v*)(o1 + (size_t)q * DD + c4);
    float4v r;
    #pragma unroll
    for (int j = 0; j < 4; ++j) r[j] = (w0 * a[j] + w1 * b[j]) * inv;
    *(float4v*)(out + (size_t)q * DD + c4) = r;
}

extern "C" void kernel_launch(void* const* d_in, const int* in_sizes, int n_in,
                              void* d_out, int out_size, void* d_ws, size_t ws_size,
                              hipStream_t stream) {
    const float* X = (const float*)d_in[0];
    const float* s = (const float*)d_in[1];
    float* out = (float*)d_out;

    _Float16* Kh = (_Float16*)d_ws;                      // 16 MiB
    _Float16* Vt = Kh + (size_t)KPAD * DD;               // 16 MiB
    float* opart0 = (float*)((char*)d_ws + (size_t)2 * KPAD * DD * 2);
    float* opart1 = opart0 + (size_t)KPAD * DD;          // 32 MiB each
    float* mlbuf  = opart1 + (size_t)KPAD * DD;          // 128 KiB

    size_t need = (size_t)2 * KPAD * DD * 2              // Kh + Vt fp16
                + (size_t)2 * KPAD * DD * 4              // opart0/1 f32
                + (size_t)2 * KPAD * 2 * 4;              // m,l
    int split = (ws_size >= need) ? 1 : 0;

    prep_k<<<(KPAD * DD) / 256, 256, 0, stream>>>(X, Kh);
    prep_vt<<<dim3(DD / 64, KPAD / 64), dim3(64, 4), 0, stream>>>(X, Vt);

    if (split) {
        flash<<<256, 512, 0, stream>>>(s, Kh, Vt, opart0, mlbuf, 64, 1);
        combine<<<NQ, 256, 0, stream>>>(opart0, opart1, mlbuf, out);
    } else {
        flash<<<128, 512, 0, stream>>>(s, Kh, Vt, out, nullptr, 128, 0);
    }
}

// Round 5
// 2611.444 us; speedup vs baseline: 1.3784x; 1.3705x over previous
//
#include <hip/hip_runtime.h>
#include <hip/hip_fp16.h>
#include <math.h>

// out = softmax(s @ X[:-1]^T) @ X[1:]
// R5: BQ=64 flash with Q in LDS (159.5 KB of the 160 KiB/CU), split-K x2.
// 8 waves: QK^T phase = 4 q-bands x 2 key-halves (no cross-wave reduction);
// PV phase = 4 q-bands x 2 D-chunks (oa = 16x512 = 128 VGPRs).
// R3/R4 lesson: 512-thr blocks cap at 256 VGPR/wave -> register-Q spilled
// (8.5 GB scratch). This design peaks ~180 VGPRs.

#define NQ 8191
#define NK 8191
#define DD 1024
#define KPAD 8192
#define BQ 64
#define BK 64
#define QS 1032     // Qs stride (halfs): 516 dw, %32=4 -> 2-way (free) on frag reads
#define SBS 68      // Sb stride (dwords)
#define PBS 72      // Pb stride (halfs)

typedef _Float16 half8 __attribute__((ext_vector_type(8)));
typedef float float4v __attribute__((ext_vector_type(4)));

__global__ void prep_k(const float* __restrict__ X, _Float16* __restrict__ Kh) {
    int idx = blockIdx.x * 256 + threadIdx.x;
    int row = idx >> 10;
    float v = (row < NK) ? X[idx] : 0.f;
    Kh[idx] = (_Float16)v;
}

__global__ void prep_vt(const float* __restrict__ X, _Float16* __restrict__ Vt) {
    __shared__ float tile[64][65];
    int d0 = blockIdx.x * 64;
    int k0 = blockIdx.y * 64;
    int tx = threadIdx.x;
    int ty = threadIdx.y;
    for (int i = 0; i < 16; ++i) {
        int k = k0 + ty * 16 + i;
        float v = (k < NK) ? X[(size_t)(k + 1) * DD + d0 + tx] : 0.f;
        tile[tx][ty * 16 + i] = v;
    }
    __syncthreads();
    for (int i = 0; i < 16; ++i) {
        int dl = ty * 16 + i;
        Vt[(size_t)(d0 + dl) * KPAD + k0 + tx] = (_Float16)tile[dl][tx];
    }
}

__launch_bounds__(512, 2)
__global__ void flash(const float* __restrict__ s,
                      const _Float16* __restrict__ Kh,
                      const _Float16* __restrict__ Vt,
                      float* __restrict__ dst,     // split: opart base; else: out
                      float* __restrict__ ml,      // split only
                      int iters, int split)
{
    __shared__ _Float16 Qs[BQ][QS];          // 132096 B
    __shared__ float    Sb[BQ][SBS];         // 17408 B   [qrow][key]
    __shared__ _Float16 Pb[BQ][PBS];         // 9216 B    [qrow][key]
    __shared__ float    mS[BQ], lS[BQ], aS[BQ];  // 768 B   -> total 159488 B

    const int t  = threadIdx.x;
    const int w  = t >> 6, l = t & 63;
    const int wr = w >> 1, wk = w & 1;       // 4 q-bands x 2 (key-half / D-chunk)
    const int ln = l & 15, q4 = l >> 4;

    int qt, kbase;
    float* dstp = dst;
    float* mlp  = ml;
    if (split) {
        int b = blockIdx.x;
        int x = b & 7, j = b >> 3;
        int ks = x & 1;                       // co-XCD blocks share a K stream
        qt    = ((x >> 1) << 5) + j;          // 0..127
        kbase = ks << 12;                     // 0 or 4096
        dstp  = dst + (size_t)ks * KPAD * DD;
        mlp   = ml  + (size_t)ks * KPAD * 2;
    } else {
        qt = blockIdx.x;
        kbase = 0;
    }
    const int q0 = qt * BQ;

    // ---- stage Q tile: fp32 global -> fp16 LDS (vectorized float4) ----
    for (int e = t; e < BQ * (DD / 4); e += 512) {
        int r = e >> 8, c = (e & 255) * 4;
        int qg = q0 + r;
        float4v f = (qg < NQ) ? *(const float4v*)(s + (size_t)qg * DD + c)
                              : (float4v){0.f, 0.f, 0.f, 0.f};
        Qs[r][c]     = (_Float16)f[0];
        Qs[r][c + 1] = (_Float16)f[1];
        Qs[r][c + 2] = (_Float16)f[2];
        Qs[r][c + 3] = (_Float16)f[3];
    }
    if (t < BQ) { mS[t] = -INFINITY; lS[t] = 0.f; }
    __syncthreads();

    // O accumulator: 16 q-rows x 512 D per wave = 128 VGPRs
    float4v oa[32];
    #pragma unroll
    for (int dt = 0; dt < 32; ++dt) oa[dt] = (float4v){0.f, 0.f, 0.f, 0.f};

    for (int it = 0; it < iters; ++it) {
        const int kb = kbase + it * BK;

        // ---- phase 1: S tile 16q x 32k per wave, full-D contraction (64 MFMA) ----
        float4v sc0 = (float4v){0.f, 0.f, 0.f, 0.f};
        float4v sc1 = (float4v){0.f, 0.f, 0.f, 0.f};
        const _Float16* kp   = Kh + (size_t)(kb + wk * 32 + ln) * DD + q4 * 8;
        const _Float16* qrow = &Qs[wr * 16 + ln][q4 * 8];
        #pragma unroll 8
        for (int f = 0; f < 32; ++f) {
            half8 a  = *(const half8*)(qrow + f * 32);
            half8 b0 = *(const half8*)(kp + f * 32);
            half8 b1 = *(const half8*)(kp + (size_t)16 * DD + f * 32);
            sc0 = __builtin_amdgcn_mfma_f32_16x16x32_f16(a, b0, sc0, 0, 0, 0);
            sc1 = __builtin_amdgcn_mfma_f32_16x16x32_f16(a, b1, sc1, 0, 0, 0);
        }
        #pragma unroll
        for (int r = 0; r < 4; ++r) {
            Sb[wr * 16 + q4 * 4 + r][wk * 32 + ln]      = sc0[r];
            Sb[wr * 16 + q4 * 4 + r][wk * 32 + 16 + ln] = sc1[r];
        }
        __syncthreads();

        // ---- phase 2: online softmax over 64 new keys ----
        {
            const int row = t >> 3, sub = t & 7;   // 64 rows x 8 threads, 8 keys each
            float sv[8];
            float tm = -INFINITY;
            #pragma unroll
            for (int j = 0; j < 8; ++j) {
                int c = sub * 8 + j;
                float v = Sb[row][c];
                v = (kb + c < NK) ? v : -INFINITY;
                sv[j] = v;
                tm = fmaxf(tm, v);
            }
            tm = fmaxf(tm, __shfl_xor(tm, 1));
            tm = fmaxf(tm, __shfl_xor(tm, 2));
            tm = fmaxf(tm, __shfl_xor(tm, 4));
            float mo = mS[row];
            float mn = fmaxf(mo, tm);
            float ts = 0.f;
            half8 ph;
            #pragma unroll
            for (int j = 0; j < 8; ++j) {
                float p = __expf(sv[j] - mn);
                ts += p;
                ph[j] = (_Float16)p;
            }
            *(half8*)&Pb[row][sub * 8] = ph;
            ts += __shfl_xor(ts, 1);
            ts += __shfl_xor(ts, 2);
            ts += __shfl_xor(ts, 4);
            if (sub == 0) {
                float al = __expf(mo - mn);
                aS[row] = al;
                mS[row] = mn;
                lS[row] = lS[row] * al + ts;
            }
        }
        __syncthreads();

        // ---- phase 3: O = O*alpha + P . V_chunk (64 MFMA; wk = D-chunk here) ----
        float al4[4];
        #pragma unroll
        for (int r = 0; r < 4; ++r) al4[r] = aS[wr * 16 + q4 * 4 + r];
        half8 ap0 = *(const half8*)&Pb[wr * 16 + ln][q4 * 8];
        half8 ap1 = *(const half8*)&Pb[wr * 16 + ln][32 + q4 * 8];
        const _Float16* vp0 = Vt + (size_t)(wk * 512 + ln) * KPAD + kb + q4 * 8;
        #pragma unroll 8
        for (int dt = 0; dt < 32; ++dt) {
            const _Float16* vp = vp0 + (size_t)dt * 16 * KPAD;
            half8 b0 = *(const half8*)vp;
            half8 b1 = *(const half8*)(vp + 32);
            float4v o = oa[dt];
            #pragma unroll
            for (int r = 0; r < 4; ++r) o[r] *= al4[r];
            o = __builtin_amdgcn_mfma_f32_16x16x32_f16(ap0, b0, o, 0, 0, 0);
            o = __builtin_amdgcn_mfma_f32_16x16x32_f16(ap1, b1, o, 0, 0, 0);
            oa[dt] = o;
        }
    }

    // ---- epilogue ----
    if (split) {
        #pragma unroll 8
        for (int dt = 0; dt < 32; ++dt) {
            #pragma unroll
            for (int r = 0; r < 4; ++r) {
                int row = q0 + wr * 16 + q4 * 4 + r;
                dstp[(size_t)row * DD + wk * 512 + dt * 16 + ln] = oa[dt][r];
            }
        }
        if (t < BQ) {
            mlp[(size_t)(q0 + t) * 2]     = mS[t];
            mlp[(size_t)(q0 + t) * 2 + 1] = lS[t];
        }
    } else {
        float li[4];
        #pragma unroll
        for (int r = 0; r < 4; ++r) li[r] = 1.f / lS[wr * 16 + q4 * 4 + r];
        #pragma unroll 8
        for (int dt = 0; dt < 32; ++dt) {
            #pragma unroll
            for (int r = 0; r < 4; ++r) {
                int row = q0 + wr * 16 + q4 * 4 + r;
                if (row < NQ)
                    dstp[(size_t)row * DD + wk * 512 + dt * 16 + ln] = oa[dt][r] * li[r];
            }
        }
    }
}

__global__ void combine(const float* __restrict__ o0,
                        const float* __restrict__ o1,
                        const float* __restrict__ ml,
                        float* __restrict__ out)
{
    int idx = blockIdx.x * 256 + threadIdx.x;   // over NQ * 256 float4s
    int q   = idx >> 8;
    int c4  = (idx & 255) * 4;
    const float* ml0 = ml;
    const float* ml1 = ml + (size_t)KPAD * 2;
    float m0 = ml0[q * 2], l0 = ml0[q * 2 + 1];
    float m1 = ml1[q * 2], l1 = ml1[q * 2 + 1];
    float mm = fmaxf(m0, m1);
    float w0 = __expf(m0 - mm), w1 = __expf(m1 - mm);
    float inv = 1.f / (w0 * l0 + w1 * l1);
    float4v a = *(const float4v*)(o0 + (size_t)q * DD + c4);
    float4v b = *(const float4v*)(o1 + (size_t)q * DD + c4);
    float4v r;
    #pragma unroll
    for (int j = 0; j < 4; ++j) r[j] = (w0 * a[j] + w1 * b[j]) * inv;
    *(float4v*)(out + (size_t)q * DD + c4) = r;
}

extern "C" void kernel_launch(void* const* d_in, const int* in_sizes, int n_in,
                              void* d_out, int out_size, void* d_ws, size_t ws_size,
                              hipStream_t stream) {
    const float* X = (const float*)d_in[0];
    const float* s = (const float*)d_in[1];
    float* out = (float*)d_out;

    _Float16* Kh = (_Float16*)d_ws;                      // 16 MiB
    _Float16* Vt = Kh + (size_t)KPAD * DD;               // 16 MiB
    float* opart0 = (float*)((char*)d_ws + (size_t)2 * KPAD * DD * 2);
    float* opart1 = opart0 + (size_t)KPAD * DD;          // 32 MiB each
    float* mlbuf  = opart1 + (size_t)KPAD * DD;          // 128 KiB

    size_t need = (size_t)2 * KPAD * DD * 2              // Kh + Vt fp16
                + (size_t)2 * KPAD * DD * 4              // opart0/1 f32
                + (size_t)2 * KPAD * 2 * 4;              // m,l
    int split = (ws_size >= need) ? 1 : 0;

    prep_k<<<(KPAD * DD) / 256, 256, 0, stream>>>(X, Kh);
    prep_vt<<<dim3(DD / 64, KPAD / 64), dim3(64, 4), 0, stream>>>(X, Vt);

    if (split) {
        flash<<<256, 512, 0, stream>>>(s, Kh, Vt, opart0, mlbuf, 64, 1);
        combine<<<NQ, 256, 0, stream>>>(opart0, opart1, mlbuf, out);
    } else {
        flash<<<128, 512, 0, stream>>>(s, Kh, Vt, out, nullptr, 128, 0);
    }
}

// Round 6
// 1954.482 us; speedup vs baseline: 1.8417x; 1.3361x over previous
//
#include <hip/hip_runtime.h>
#include <hip/hip_fp16.h>
#include <math.h>

// out = softmax(s @ X[:-1]^T) @ X[1:]
// R6: R5 structure (BQ=64, Q in LDS 156 KiB, split-K x2, 512 thr), with the
// accumulator-spill bug fixed: R3-R5 used `#pragma unroll 8` on loops that
// index oa[dt] -> partial unroll leaves a DYNAMIC index -> whole oa array
// demoted to scratch (4.3-8.5 GB of HBM scratch traffic, the real reason
// those rounds were slow). All oa-indexed loops are now FULLY unrolled.

#define NQ 8191
#define NK 8191
#define DD 1024
#define KPAD 8192
#define BQ 64
#define BK 64
#define QS 1032     // Qs stride (halfs)
#define SBS 68      // Sb stride (dwords)
#define PBS 72      // Pb stride (halfs)

typedef _Float16 half8 __attribute__((ext_vector_type(8)));
typedef float float4v __attribute__((ext_vector_type(4)));

__global__ void prep_k(const float* __restrict__ X, _Float16* __restrict__ Kh) {
    int idx = blockIdx.x * 256 + threadIdx.x;
    int row = idx >> 10;
    float v = (row < NK) ? X[idx] : 0.f;
    Kh[idx] = (_Float16)v;
}

__global__ void prep_vt(const float* __restrict__ X, _Float16* __restrict__ Vt) {
    __shared__ float tile[64][65];
    int d0 = blockIdx.x * 64;
    int k0 = blockIdx.y * 64;
    int tx = threadIdx.x;
    int ty = threadIdx.y;
    for (int i = 0; i < 16; ++i) {
        int k = k0 + ty * 16 + i;
        float v = (k < NK) ? X[(size_t)(k + 1) * DD + d0 + tx] : 0.f;
        tile[tx][ty * 16 + i] = v;
    }
    __syncthreads();
    for (int i = 0; i < 16; ++i) {
        int dl = ty * 16 + i;
        Vt[(size_t)(d0 + dl) * KPAD + k0 + tx] = (_Float16)tile[dl][tx];
    }
}

__launch_bounds__(512, 2)
__global__ void flash(const float* __restrict__ s,
                      const _Float16* __restrict__ Kh,
                      const _Float16* __restrict__ Vt,
                      float* __restrict__ dst,     // split: opart base; else: out
                      float* __restrict__ ml,      // split only
                      int iters, int split)
{
    __shared__ _Float16 Qs[BQ][QS];          // 132096 B
    __shared__ float    Sb[BQ][SBS];         // 17408 B   [qrow][key]
    __shared__ _Float16 Pb[BQ][PBS];         // 9216 B    [qrow][key]
    __shared__ float    mS[BQ], lS[BQ], aS[BQ];  // 768 B  -> total 159488 B

    const int t  = threadIdx.x;
    const int w  = t >> 6, l = t & 63;
    const int wr = w >> 1, wk = w & 1;       // 4 q-bands x 2 (key-half / D-chunk)
    const int ln = l & 15, q4 = l >> 4;

    int qt, kbase;
    float* dstp = dst;
    float* mlp  = ml;
    if (split) {
        int b = blockIdx.x;
        int x = b & 7, j = b >> 3;
        int ks = x & 1;                       // co-XCD blocks share a K stream
        qt    = ((x >> 1) << 5) + j;          // 0..127
        kbase = ks << 12;                     // 0 or 4096
        dstp  = dst + (size_t)ks * KPAD * DD;
        mlp   = ml  + (size_t)ks * KPAD * 2;
    } else {
        qt = blockIdx.x;
        kbase = 0;
    }
    const int q0 = qt * BQ;

    // ---- stage Q tile: fp32 global -> fp16 LDS ----
    for (int e = t; e < BQ * (DD / 4); e += 512) {
        int r = e >> 8, c = (e & 255) * 4;
        int qg = q0 + r;
        float4v f = (qg < NQ) ? *(const float4v*)(s + (size_t)qg * DD + c)
                              : (float4v){0.f, 0.f, 0.f, 0.f};
        Qs[r][c]     = (_Float16)f[0];
        Qs[r][c + 1] = (_Float16)f[1];
        Qs[r][c + 2] = (_Float16)f[2];
        Qs[r][c + 3] = (_Float16)f[3];
    }
    if (t < BQ) { mS[t] = -INFINITY; lS[t] = 0.f; }
    __syncthreads();

    // O accumulator: 16 q-rows x 512 D per wave = 128 regs. Every loop that
    // touches oa[] below is FULLY unrolled (dynamic index => scratch demotion).
    float4v oa[32];
    #pragma unroll
    for (int dt = 0; dt < 32; ++dt) oa[dt] = (float4v){0.f, 0.f, 0.f, 0.f};

    for (int it = 0; it < iters; ++it) {
        const int kb = kbase + it * BK;

        // ---- phase 1: S tile 16q x 32k per wave, full-D contraction ----
        float4v sc0 = (float4v){0.f, 0.f, 0.f, 0.f};
        float4v sc1 = (float4v){0.f, 0.f, 0.f, 0.f};
        const _Float16* kp   = Kh + (size_t)(kb + wk * 32 + ln) * DD + q4 * 8;
        const _Float16* qrow = &Qs[wr * 16 + ln][q4 * 8];
        #pragma unroll 8
        for (int f = 0; f < 32; ++f) {       // scalars only -> partial unroll ok
            half8 a  = *(const half8*)(qrow + f * 32);
            half8 b0 = *(const half8*)(kp + f * 32);
            half8 b1 = *(const half8*)(kp + (size_t)16 * DD + f * 32);
            sc0 = __builtin_amdgcn_mfma_f32_16x16x32_f16(a, b0, sc0, 0, 0, 0);
            sc1 = __builtin_amdgcn_mfma_f32_16x16x32_f16(a, b1, sc1, 0, 0, 0);
        }
        #pragma unroll
        for (int r = 0; r < 4; ++r) {
            Sb[wr * 16 + q4 * 4 + r][wk * 32 + ln]      = sc0[r];
            Sb[wr * 16 + q4 * 4 + r][wk * 32 + 16 + ln] = sc1[r];
        }
        __syncthreads();

        // ---- phase 2: online softmax over 64 new keys ----
        {
            const int row = t >> 3, sub = t & 7;
            float sv[8];
            float tm = -INFINITY;
            #pragma unroll
            for (int j = 0; j < 8; ++j) {
                int c = sub * 8 + j;
                float v = Sb[row][c];
                v = (kb + c < NK) ? v : -INFINITY;
                sv[j] = v;
                tm = fmaxf(tm, v);
            }
            tm = fmaxf(tm, __shfl_xor(tm, 1));
            tm = fmaxf(tm, __shfl_xor(tm, 2));
            tm = fmaxf(tm, __shfl_xor(tm, 4));
            float mo = mS[row];
            float mn = fmaxf(mo, tm);
            float ts = 0.f;
            half8 ph;
            #pragma unroll
            for (int j = 0; j < 8; ++j) {
                float p = __expf(sv[j] - mn);
                ts += p;
                ph[j] = (_Float16)p;
            }
            *(half8*)&Pb[row][sub * 8] = ph;
            ts += __shfl_xor(ts, 1);
            ts += __shfl_xor(ts, 2);
            ts += __shfl_xor(ts, 4);
            if (sub == 0) {
                float al = __expf(mo - mn);
                aS[row] = al;
                mS[row] = mn;
                lS[row] = lS[row] * al + ts;
            }
        }
        __syncthreads();

        // ---- phase 3: O = O*alpha + P . V_chunk (FULL unroll over oa) ----
        float al4[4];
        #pragma unroll
        for (int r = 0; r < 4; ++r) al4[r] = aS[wr * 16 + q4 * 4 + r];
        half8 ap0 = *(const half8*)&Pb[wr * 16 + ln][q4 * 8];
        half8 ap1 = *(const half8*)&Pb[wr * 16 + ln][32 + q4 * 8];
        const _Float16* vp0 = Vt + (size_t)(wk * 512 + ln) * KPAD + kb + q4 * 8;
        #pragma unroll
        for (int dt = 0; dt < 32; ++dt) {
            const _Float16* vp = vp0 + (size_t)dt * 16 * KPAD;
            half8 b0 = *(const half8*)vp;
            half8 b1 = *(const half8*)(vp + 32);
            float4v o = oa[dt];
            #pragma unroll
            for (int r = 0; r < 4; ++r) o[r] *= al4[r];
            o = __builtin_amdgcn_mfma_f32_16x16x32_f16(ap0, b0, o, 0, 0, 0);
            o = __builtin_amdgcn_mfma_f32_16x16x32_f16(ap1, b1, o, 0, 0, 0);
            oa[dt] = o;
        }
    }

    // ---- epilogue (FULL unroll over oa) ----
    if (split) {
        #pragma unroll
        for (int dt = 0; dt < 32; ++dt) {
            #pragma unroll
            for (int r = 0; r < 4; ++r) {
                int row = q0 + wr * 16 + q4 * 4 + r;
                dstp[(size_t)row * DD + wk * 512 + dt * 16 + ln] = oa[dt][r];
            }
        }
        if (t < BQ) {
            mlp[(size_t)(q0 + t) * 2]     = mS[t];
            mlp[(size_t)(q0 + t) * 2 + 1] = lS[t];
        }
    } else {
        float li[4];
        #pragma unroll
        for (int r = 0; r < 4; ++r) li[r] = 1.f / lS[wr * 16 + q4 * 4 + r];
        #pragma unroll
        for (int dt = 0; dt < 32; ++dt) {
            #pragma unroll
            for (int r = 0; r < 4; ++r) {
                int row = q0 + wr * 16 + q4 * 4 + r;
                if (row < NQ)
                    dstp[(size_t)row * DD + wk * 512 + dt * 16 + ln] = oa[dt][r] * li[r];
            }
        }
    }
}

__global__ void combine(const float* __restrict__ o0,
                        const float* __restrict__ o1,
                        const float* __restrict__ ml,
                        float* __restrict__ out)
{
    int idx = blockIdx.x * 256 + threadIdx.x;   // over NQ * 256 float4s
    int q   = idx >> 8;
    int c4  = (idx & 255) * 4;
    const float* ml0 = ml;
    const float* ml1 = ml + (size_t)KPAD * 2;
    float m0 = ml0[q * 2], l0 = ml0[q * 2 + 1];
    float m1 = ml1[q * 2], l1 = ml1[q * 2 + 1];
    float mm = fmaxf(m0, m1);
    float w0 = __expf(m0 - mm), w1 = __expf(m1 - mm);
    float inv = 1.f / (w0 * l0 + w1 * l1);
    float4v a = *(const float4v*)(o0 + (size_t)q * DD + c4);
    float4v b = *(const float4v*)(o1 + (size_t)q * DD + c4);
    float4v r;
    #pragma unroll
    for (int j = 0; j < 4; ++j) r[j] = (w0 * a[j] + w1 * b[j]) * inv;
    *(float4v*)(out + (size_t)q * DD + c4) = r;
}

extern "C" void kernel_launch(void* const* d_in, const int* in_sizes, int n_in,
                              void* d_out, int out_size, void* d_ws, size_t ws_size,
                              hipStream_t stream) {
    const float* X = (const float*)d_in[0];
    const float* s = (const float*)d_in[1];
    float* out = (float*)d_out;

    _Float16* Kh = (_Float16*)d_ws;                      // 16 MiB
    _Float16* Vt = Kh + (size_t)KPAD * DD;               // 16 MiB
    float* opart0 = (float*)((char*)d_ws + (size_t)2 * KPAD * DD * 2);
    float* opart1 = opart0 + (size_t)KPAD * DD;          // 32 MiB each
    float* mlbuf  = opart1 + (size_t)KPAD * DD;          // 128 KiB

    size_t need = (size_t)2 * KPAD * DD * 2              // Kh + Vt fp16
                + (size_t)2 * KPAD * DD * 4              // opart0/1 f32
                + (size_t)2 * KPAD * 2 * 4;              // m,l
    int split = (ws_size >= need) ? 1 : 0;

    prep_k<<<(KPAD * DD) / 256, 256, 0, stream>>>(X, Kh);
    prep_vt<<<dim3(DD / 64, KPAD / 64), dim3(64, 4), 0, stream>>>(X, Vt);

    if (split) {
        flash<<<256, 512, 0, stream>>>(s, Kh, Vt, opart0, mlbuf, 64, 1);
        combine<<<NQ, 256, 0, stream>>>(opart0, opart1, mlbuf, out);
    } else {
        flash<<<128, 512, 0, stream>>>(s, Kh, Vt, out, nullptr, 128, 0);
    }
}